// Round 1
// baseline (237.156 us; speedup 1.0000x reference)
//
#include <hip/hip_runtime.h>

// AGNNConv: out = segsum(exp(aw * <Xp[row],Xp[col]>) * Xp[col]) / segsum(exp(...))
// Xp = X @ W.  N=100000, E=1200000, D=64 (== wavefront size).

// ---------------- GEMM: Xp = X @ W (f32, K=64, no f32 MFMA on CDNA4) -------
// Each lane owns W column `lane` in registers; X row broadcast via readlane.
__global__ __launch_bounds__(256) void gemm_xw(
    const float* __restrict__ X, const float* __restrict__ W,
    float* __restrict__ Xp, int N)
{
    const int lane  = threadIdx.x & 63;
    const int gwave = (int)((blockIdx.x * blockDim.x + threadIdx.x) >> 6);
    const int nwave = (int)((gridDim.x * blockDim.x) >> 6);

    float w[64];
#pragma unroll
    for (int k = 0; k < 64; ++k) w[k] = W[(k << 6) + lane];   // coalesced, L2-hot

    for (int r = gwave; r < N; r += nwave) {
        float x = X[(size_t)r * 64 + lane];                   // coalesced
        float a0 = 0.f, a1 = 0.f, a2 = 0.f, a3 = 0.f;
#pragma unroll
        for (int k = 0; k < 64; k += 4) {
            a0 = fmaf(__uint_as_float(__builtin_amdgcn_readlane(__float_as_uint(x), k + 0)), w[k + 0], a0);
            a1 = fmaf(__uint_as_float(__builtin_amdgcn_readlane(__float_as_uint(x), k + 1)), w[k + 1], a1);
            a2 = fmaf(__uint_as_float(__builtin_amdgcn_readlane(__float_as_uint(x), k + 2)), w[k + 2], a2);
            a3 = fmaf(__uint_as_float(__builtin_amdgcn_readlane(__float_as_uint(x), k + 3)), w[k + 3], a3);
        }
        Xp[(size_t)r * 64 + lane] = (a0 + a1) + (a2 + a3);    // coalesced
    }
}

// ---------------- CSR row_ptr from sorted row[] (every row non-empty) ------
__global__ void build_rowptr(const int* __restrict__ row, int* __restrict__ rp,
                             int E, int N)
{
    int e = blockIdx.x * blockDim.x + threadIdx.x;
    if (e >= E) return;
    int r = row[e];
    if (e == 0)                rp[r] = 0;      // row[0]==0 (self-loops, sorted)
    else if (row[e - 1] != r)  rp[r] = e;
    if (e == E - 1)            rp[N] = E;
}

// ---------------- full-wave (64-lane) sum via DPP (VALU pipe, no LDS) ------
__device__ __forceinline__ float dpp_wave_sum_bcast(float x)
{
    // rocPRIM gfx9 wf64 reduce pattern; valid partial sum only at lane 63.
    x += __uint_as_float(__builtin_amdgcn_update_dpp(
        __float_as_uint(x), __float_as_uint(x), 0x111, 0xf, 0xf, false)); // row_shr:1
    x += __uint_as_float(__builtin_amdgcn_update_dpp(
        __float_as_uint(x), __float_as_uint(x), 0x112, 0xf, 0xf, false)); // row_shr:2
    x += __uint_as_float(__builtin_amdgcn_update_dpp(
        __float_as_uint(x), __float_as_uint(x), 0x114, 0xf, 0xe, false)); // row_shr:4
    x += __uint_as_float(__builtin_amdgcn_update_dpp(
        __float_as_uint(x), __float_as_uint(x), 0x118, 0xf, 0xc, false)); // row_shr:8
    x += __uint_as_float(__builtin_amdgcn_update_dpp(
        __float_as_uint(x), __float_as_uint(x), 0x142, 0xa, 0xf, false)); // row_bcast:15
    x += __uint_as_float(__builtin_amdgcn_update_dpp(
        __float_as_uint(x), __float_as_uint(x), 0x143, 0xc, 0xf, false)); // row_bcast:31
    // broadcast lane 63 to all lanes (lands in SGPR)
    return __uint_as_float(__builtin_amdgcn_readlane(__float_as_uint(x), 63));
}

// ---------------- aggregation: one wave per row, lane == feature dim -------
__global__ __launch_bounds__(256) void agg(
    const float* __restrict__ Xp, const int* __restrict__ rp,
    const int* __restrict__ col, const float* __restrict__ attw,
    float* __restrict__ out, int N)
{
    const int lane = threadIdx.x & 63;
    const int r    = (int)((blockIdx.x * blockDim.x + threadIdx.x) >> 6);
    if (r >= N) return;

    const float aw    = attw[0];
    const int   start = rp[r];
    const int   end   = rp[r + 1];            // >= start+1 (self-loop)
    const float xr    = Xp[(size_t)r * 64 + lane];

    float acc = 0.f, rs = 0.f;

    // software prefetch one edge ahead (hide L2/L3 gather latency)
    int   cN  = col[start];
    float xcN = Xp[(size_t)cN * 64 + lane];

    for (int e = start; e < end; ++e) {
        float xc = xcN;
        if (e + 1 < end) {
            int c2 = col[e + 1];
            xcN = Xp[(size_t)c2 * 64 + lane];
        }
        float s   = dpp_wave_sum_bcast(xr * xc);   // <Xp[row], Xp[col]>
        float att = __expf(s * aw);
        acc = fmaf(att, xc, acc);
        rs += att;
    }
    out[(size_t)r * 64 + lane] = acc / rs;
}

// ---------------------------------------------------------------------------
extern "C" void kernel_launch(void* const* d_in, const int* in_sizes, int n_in,
                              void* d_out, int out_size, void* d_ws, size_t ws_size,
                              hipStream_t stream)
{
    const float* X    = (const float*)d_in[0];
    const float* W    = (const float*)d_in[1];
    const float* attw = (const float*)d_in[2];
    const int*   row  = (const int*)d_in[3];
    const int*   col  = (const int*)d_in[4];
    float*       out  = (float*)d_out;

    const int N = in_sizes[0] / 64;
    const int E = in_sizes[3];

    float* Xp = (float*)d_ws;                                   // N*64 f32 = 25.6 MB
    int*   rp = (int*)((char*)d_ws + (size_t)N * 64 * sizeof(float)); // N+1 ints

    gemm_xw<<<1024, 256, 0, stream>>>(X, W, Xp, N);
    build_rowptr<<<(E + 255) / 256, 256, 0, stream>>>(row, rp, E, N);
    agg<<<(N + 3) / 4, 256, 0, stream>>>(Xp, rp, col, attw, out, N);
}

// Round 2
// 191.086 us; speedup vs baseline: 1.2411x; 1.2411x over previous
//
#include <hip/hip_runtime.h>
#include <hip/hip_bf16.h>

// AGNNConv: out = segsum(exp(aw * <Xp[row],Xp[col]>) * Xp[col]) / segsum(exp(...))
// Xp = X @ W.  N=100000, E=1200000, D=64 (== wavefront size).
// Xp stored in workspace as bf16: halves gather bytes, doubles L2 coverage.

// ---------------- GEMM: Xp = X @ W (f32 compute, bf16 store) ---------------
// Each lane owns W column `lane` in registers; X row broadcast via readlane.
__global__ __launch_bounds__(256) void gemm_xw(
    const float* __restrict__ X, const float* __restrict__ W,
    __hip_bfloat16* __restrict__ Xpb, int N)
{
    const int lane  = threadIdx.x & 63;
    const int gwave = (int)((blockIdx.x * blockDim.x + threadIdx.x) >> 6);
    const int nwave = (int)((gridDim.x * blockDim.x) >> 6);

    float w[64];
#pragma unroll
    for (int k = 0; k < 64; ++k) w[k] = W[(k << 6) + lane];   // coalesced, L2-hot

    for (int r = gwave; r < N; r += nwave) {
        float x = X[(size_t)r * 64 + lane];                   // coalesced
        float a0 = 0.f, a1 = 0.f, a2 = 0.f, a3 = 0.f;
#pragma unroll
        for (int k = 0; k < 64; k += 4) {
            a0 = fmaf(__uint_as_float(__builtin_amdgcn_readlane(__float_as_uint(x), k + 0)), w[k + 0], a0);
            a1 = fmaf(__uint_as_float(__builtin_amdgcn_readlane(__float_as_uint(x), k + 1)), w[k + 1], a1);
            a2 = fmaf(__uint_as_float(__builtin_amdgcn_readlane(__float_as_uint(x), k + 2)), w[k + 2], a2);
            a3 = fmaf(__uint_as_float(__builtin_amdgcn_readlane(__float_as_uint(x), k + 3)), w[k + 3], a3);
        }
        Xpb[(size_t)r * 64 + lane] = __float2bfloat16((a0 + a1) + (a2 + a3));
    }
}

// ---------------- CSR row_ptr from sorted row[] (every row non-empty) ------
__global__ void build_rowptr(const int* __restrict__ row, int* __restrict__ rp,
                             int E, int N)
{
    int e = blockIdx.x * blockDim.x + threadIdx.x;
    if (e >= E) return;
    int r = row[e];
    if (e == 0)                rp[r] = 0;
    else if (row[e - 1] != r)  rp[r] = e;
    if (e == E - 1)            rp[N] = E;
}

// ---------------- full-wave (64-lane) sum via DPP (VALU pipe, no LDS) ------
__device__ __forceinline__ float dpp_wave_sum_bcast(float x)
{
    x += __uint_as_float(__builtin_amdgcn_update_dpp(
        __float_as_uint(x), __float_as_uint(x), 0x111, 0xf, 0xf, false)); // row_shr:1
    x += __uint_as_float(__builtin_amdgcn_update_dpp(
        __float_as_uint(x), __float_as_uint(x), 0x112, 0xf, 0xf, false)); // row_shr:2
    x += __uint_as_float(__builtin_amdgcn_update_dpp(
        __float_as_uint(x), __float_as_uint(x), 0x114, 0xf, 0xe, false)); // row_shr:4
    x += __uint_as_float(__builtin_amdgcn_update_dpp(
        __float_as_uint(x), __float_as_uint(x), 0x118, 0xf, 0xc, false)); // row_shr:8
    x += __uint_as_float(__builtin_amdgcn_update_dpp(
        __float_as_uint(x), __float_as_uint(x), 0x142, 0xa, 0xf, false)); // row_bcast:15
    x += __uint_as_float(__builtin_amdgcn_update_dpp(
        __float_as_uint(x), __float_as_uint(x), 0x143, 0xc, 0xf, false)); // row_bcast:31
    return __uint_as_float(__builtin_amdgcn_readlane(__float_as_uint(x), 63));
}

__device__ __forceinline__ float bf2f(unsigned short u)
{
    return __uint_as_float(((unsigned int)u) << 16);
}

// ---------------- aggregation: one wave per row, lane == feature dim -------
// 8-edge packets with explicit next-packet prefetch: 8 outstanding gathers
// per wave (was 1). Tail edges handled by clamped index + zero-masked att.
__global__ __launch_bounds__(256) void agg(
    const unsigned short* __restrict__ Xpb, const int* __restrict__ rp,
    const int* __restrict__ col, const float* __restrict__ attw,
    float* __restrict__ out, int N)
{
    const int lane = threadIdx.x & 63;
    const int r    = (int)((blockIdx.x * blockDim.x + threadIdx.x) >> 6);
    if (r >= N) return;

    const float aw    = attw[0];
    const int   start = rp[r];
    const int   end   = rp[r + 1];                 // >= start+1 (self-loop)
    const unsigned short* Xl = Xpb + lane;         // lane-offset base
    const float xr = bf2f(Xl[(size_t)r << 6]);

    float acc = 0.f, rs = 0.f;

    int   c[8];
    float x[8];
#pragma unroll
    for (int i = 0; i < 8; ++i) {
        int ei = start + i;
        c[i] = col[ei < end ? ei : end - 1];
    }
#pragma unroll
    for (int i = 0; i < 8; ++i) x[i] = bf2f(Xl[(size_t)c[i] << 6]);

    for (int e = start; e < end; e += 8) {
        int   nc[8];
        float nx[8];
        const bool more = (e + 8) < end;
        if (more) {
#pragma unroll
            for (int i = 0; i < 8; ++i) {
                int ei = e + 8 + i;
                nc[i] = col[ei < end ? ei : end - 1];
            }
#pragma unroll
            for (int i = 0; i < 8; ++i) nx[i] = bf2f(Xl[(size_t)nc[i] << 6]);
        }

        float a[8];
#pragma unroll
        for (int i = 0; i < 8; ++i) {
            float s   = dpp_wave_sum_bcast(xr * x[i]);   // <Xp[row], Xp[col]>
            float att = __expf(s * aw);
            a[i] = (e + i) < end ? att : 0.f;            // mask padded slots
        }
#pragma unroll
        for (int i = 0; i < 8; ++i) {
            acc = fmaf(a[i], x[i], acc);
            rs += a[i];
        }
        if (more) {
#pragma unroll
            for (int i = 0; i < 8; ++i) { c[i] = nc[i]; x[i] = nx[i]; }
        }
    }
    out[((size_t)r << 6) + lane] = acc / rs;
}

// ---------------------------------------------------------------------------
extern "C" void kernel_launch(void* const* d_in, const int* in_sizes, int n_in,
                              void* d_out, int out_size, void* d_ws, size_t ws_size,
                              hipStream_t stream)
{
    const float* X    = (const float*)d_in[0];
    const float* W    = (const float*)d_in[1];
    const float* attw = (const float*)d_in[2];
    const int*   row  = (const int*)d_in[3];
    const int*   col  = (const int*)d_in[4];
    float*       out  = (float*)d_out;

    const int N = in_sizes[0] / 64;
    const int E = in_sizes[3];

    __hip_bfloat16* Xpb = (__hip_bfloat16*)d_ws;                    // N*64 bf16 = 12.8 MB
    int* rp = (int*)((char*)d_ws + (size_t)N * 64 * sizeof(__hip_bfloat16)); // N+1 ints

    gemm_xw<<<2048, 256, 0, stream>>>(X, W, Xpb, N);
    build_rowptr<<<(E + 255) / 256, 256, 0, stream>>>(row, rp, E, N);
    agg<<<(N + 3) / 4, 256, 0, stream>>>((const unsigned short*)Xpb, rp, col,
                                         attw, out, N);
}

// Round 3
// 126.149 us; speedup vs baseline: 1.8800x; 1.5148x over previous
//
#include <hip/hip_runtime.h>

// AGNNConv on gfx950:
//   Xp = bf16(X @ W)                (MFMA 16x16x32 bf16, fused with rowptr build)
//   out[r] = sum_e exp(aw*<Xp[r],Xp[c]>)*Xp[c] / sum_e exp(...)
// N=100000, E=1200000, D=64.

typedef __attribute__((ext_vector_type(8))) short short8;
typedef __attribute__((ext_vector_type(4))) float f32x4;

__device__ __forceinline__ unsigned short f2bf(float f) {   // RNE f32->bf16
    unsigned u = __float_as_uint(f);
    return (unsigned short)((u + 0x7fffu + ((u >> 16) & 1u)) >> 16);
}
__device__ __forceinline__ float blo(unsigned u) { return __uint_as_float(u << 16); }
__device__ __forceinline__ float bhi(unsigned u) { return __uint_as_float(u & 0xffff0000u); }

// ---- K1: fused CSR rowptr build + Xp = bf16(X @ W) via MFMA ---------------
// 16 rows per block; 4 waves, wave w -> cols [16w,16w+16). K=64 = 2 MFMA steps.
__global__ __launch_bounds__(256) void gemm_rowptr(
    const float* __restrict__ X, const float* __restrict__ W,
    const int* __restrict__ row, unsigned short* __restrict__ Xpb,
    int* __restrict__ rp, int N, int E)
{
    // rowptr: one edge per thread (row[] sorted, every row non-empty)
    {
        int e = blockIdx.x * 256 + threadIdx.x;
        if (e < E) {
            int r = row[e];
            if (e == 0)                rp[r] = 0;
            else if (row[e - 1] != r)  rp[r] = e;
            if (e == E - 1)            rp[N] = E;
        }
    }

    const int r0 = blockIdx.x * 16;
    if (r0 >= N) return;

    const int lane = threadIdx.x & 63;
    const int wv   = threadIdx.x >> 6;       // 0..3: col block
    const int m    = lane & 15;              // A-row / B-col / D-col
    const int kb   = (lane >> 4) << 3;       // k-base: 0,8,16,24

    // A fragments: lane holds X[r0+m][kb + j (+32)]
    const float* xr = X + (size_t)(r0 + m) * 64 + kb;
    float4 aL0 = *(const float4*)(xr);
    float4 aH0 = *(const float4*)(xr + 4);
    float4 aL1 = *(const float4*)(xr + 32);
    float4 aH1 = *(const float4*)(xr + 36);
    short8 a0, a1;
    a0[0]=f2bf(aL0.x); a0[1]=f2bf(aL0.y); a0[2]=f2bf(aL0.z); a0[3]=f2bf(aL0.w);
    a0[4]=f2bf(aH0.x); a0[5]=f2bf(aH0.y); a0[6]=f2bf(aH0.z); a0[7]=f2bf(aH0.w);
    a1[0]=f2bf(aL1.x); a1[1]=f2bf(aL1.y); a1[2]=f2bf(aL1.z); a1[3]=f2bf(aL1.w);
    a1[4]=f2bf(aH1.x); a1[5]=f2bf(aH1.y); a1[6]=f2bf(aH1.z); a1[7]=f2bf(aH1.w);

    // B fragments: lane holds W[kb + j (+32)][16*wv + m]
    const float* wc = W + (size_t)kb * 64 + 16 * wv + m;
    short8 b0, b1;
#pragma unroll
    for (int j = 0; j < 8; ++j) b0[j] = f2bf(wc[j * 64]);
#pragma unroll
    for (int j = 0; j < 8; ++j) b1[j] = f2bf(wc[(j + 32) * 64]);

    f32x4 acc = {0.f, 0.f, 0.f, 0.f};
    acc = __builtin_amdgcn_mfma_f32_16x16x32_bf16(a0, b0, acc, 0, 0, 0);
    acc = __builtin_amdgcn_mfma_f32_16x16x32_bf16(a1, b1, acc, 0, 0, 0);

    // D: col = 16*wv + m, row = r0 + (lane>>4)*4 + j
    unsigned short* o = Xpb + (size_t)(r0 + ((lane >> 4) << 2)) * 64 + 16 * wv + m;
#pragma unroll
    for (int j = 0; j < 4; ++j) o[j * 64] = f2bf(acc[j]);
}

// ---- K2: aggregation. 4 rows/wave, 16 lanes/row, 4 bf16 features/lane -----
// Every wave instruction serves 4 edges (one per row-group). Reduce within
// 16-lane group = 4 x ds_swizzle xor butterfly (LDS pipe). Depth-2 pipeline:
// cols prefetched 2 packets ahead, gathers 1 packet ahead, branchless clamp.
#define AGG_STEP(G, OFF)                                                          \
    {                                                                             \
        float x0 = blo(G.x), x1 = bhi(G.x), x2 = blo(G.y), x3 = bhi(G.y);         \
        float p = x0 * xr0;                                                       \
        p = fmaf(x1, xr1, p);                                                     \
        p = fmaf(x2, xr2, p);                                                     \
        p = fmaf(x3, xr3, p);                                                     \
        p += __int_as_float(__builtin_amdgcn_ds_swizzle(__float_as_int(p), 0x041F)); \
        p += __int_as_float(__builtin_amdgcn_ds_swizzle(__float_as_int(p), 0x081F)); \
        p += __int_as_float(__builtin_amdgcn_ds_swizzle(__float_as_int(p), 0x101F)); \
        p += __int_as_float(__builtin_amdgcn_ds_swizzle(__float_as_int(p), 0x201F)); \
        float att = __expf(p * aw);                                               \
        att = (e + OFF < end) ? att : 0.f;                                        \
        acc0 = fmaf(att, x0, acc0);                                               \
        acc1 = fmaf(att, x1, acc1);                                               \
        acc2 = fmaf(att, x2, acc2);                                               \
        acc3 = fmaf(att, x3, acc3);                                               \
        rs += att;                                                                \
    }

__global__ __launch_bounds__(256) void agg(
    const unsigned short* __restrict__ Xpb, const int* __restrict__ rp,
    const int* __restrict__ col, const float* __restrict__ attw,
    float* __restrict__ out, int N)
{
    const int lane = threadIdx.x & 63;
    const int t    = lane & 15;                                   // pos in group
    const int wid  = (int)((blockIdx.x * blockDim.x + threadIdx.x) >> 6);
    const int r    = (wid << 2) + (lane >> 4);
    if ((wid << 2) >= N) return;
    const int  rr    = (r < N) ? r : (N - 1);
    const bool rowok = (r < N);

    const float aw    = attw[0];
    const int   start = rp[rr];
    const int   end   = rowok ? rp[rr + 1] : start;
    const int   cap   = (end > start) ? (end - 1) : start;        // clamp target

    const char* xb = (const char*)Xpb + (t << 3);                 // lane byte base
    uint2 xw = *(const uint2*)(xb + ((size_t)rr << 7));
    const float xr0 = blo(xw.x), xr1 = bhi(xw.x), xr2 = blo(xw.y), xr3 = bhi(xw.y);

    float acc0 = 0.f, acc1 = 0.f, acc2 = 0.f, acc3 = 0.f, rs = 0.f;

    // pipeline prologue: current packet gathers + next packet cols
    int c0 = col[min(start,     cap)];
    int c1 = col[min(start + 1, cap)];
    int c2 = col[min(start + 2, cap)];
    int c3 = col[min(start + 3, cap)];
    uint2 g0 = *(const uint2*)(xb + ((size_t)c0 << 7));
    uint2 g1 = *(const uint2*)(xb + ((size_t)c1 << 7));
    uint2 g2 = *(const uint2*)(xb + ((size_t)c2 << 7));
    uint2 g3 = *(const uint2*)(xb + ((size_t)c3 << 7));
    int n0 = col[min(start + 4, cap)];
    int n1 = col[min(start + 5, cap)];
    int n2 = col[min(start + 6, cap)];
    int n3 = col[min(start + 7, cap)];

    for (int e = start; e < end; e += 4) {
        // issue next packet's gathers (cols already resident)
        uint2 h0 = *(const uint2*)(xb + ((size_t)n0 << 7));
        uint2 h1 = *(const uint2*)(xb + ((size_t)n1 << 7));
        uint2 h2 = *(const uint2*)(xb + ((size_t)n2 << 7));
        uint2 h3 = *(const uint2*)(xb + ((size_t)n3 << 7));
        // issue cols two packets ahead
        int m0 = col[min(e +  8, cap)];
        int m1 = col[min(e +  9, cap)];
        int m2 = col[min(e + 10, cap)];
        int m3 = col[min(e + 11, cap)];

        AGG_STEP(g0, 0)
        AGG_STEP(g1, 1)
        AGG_STEP(g2, 2)
        AGG_STEP(g3, 3)

        g0 = h0; g1 = h1; g2 = h2; g3 = h3;
        n0 = m0; n1 = m1; n2 = m2; n3 = m3;
    }

    if (rowok) {
        float inv = 1.0f / rs;
        *(float4*)(out + ((size_t)r << 6) + (t << 2)) =
            make_float4(acc0 * inv, acc1 * inv, acc2 * inv, acc3 * inv);
    }
}

// ---------------------------------------------------------------------------
extern "C" void kernel_launch(void* const* d_in, const int* in_sizes, int n_in,
                              void* d_out, int out_size, void* d_ws, size_t ws_size,
                              hipStream_t stream)
{
    const float* X    = (const float*)d_in[0];
    const float* W    = (const float*)d_in[1];
    const float* attw = (const float*)d_in[2];
    const int*   row  = (const int*)d_in[3];
    const int*   col  = (const int*)d_in[4];
    float*       out  = (float*)d_out;

    const int N = in_sizes[0] / 64;
    const int E = in_sizes[3];

    unsigned short* Xpb = (unsigned short*)d_ws;                       // N*64 bf16
    int* rp = (int*)((char*)d_ws + (size_t)N * 64 * sizeof(unsigned short));

    int gb1 = max((N + 15) / 16, (E + 255) / 256);
    gemm_rowptr<<<gb1, 256, 0, stream>>>(X, W, row, Xpb, rp, N, E);

    int waves = (N + 3) / 4;
    int gb2   = (waves * 64 + 255) / 256;
    agg<<<gb2, 256, 0, stream>>>(Xpb, rp, col, attw, out, N);
}

// Round 4
// 124.751 us; speedup vs baseline: 1.9010x; 1.0112x over previous
//
#include <hip/hip_runtime.h>

// AGNNConv on gfx950:
//   Xp = bf16(X @ W)   (MFMA 16x16x32 bf16; B fragments hoisted, rowptr fused)
//   out[r] = sum_e exp(aw*<Xp[r],Xp[c]>)*Xp[c] / sum_e exp(...)
// N=100000, E=1200000, D=64.

typedef __attribute__((ext_vector_type(8))) short short8;
typedef __attribute__((ext_vector_type(4))) float f32x4;

__device__ __forceinline__ unsigned short f2bf(float f) {   // RNE f32->bf16
    unsigned u = __float_as_uint(f);
    return (unsigned short)((u + 0x7fffu + ((u >> 16) & 1u)) >> 16);
}
__device__ __forceinline__ float blo(unsigned u) { return __uint_as_float(u << 16); }
__device__ __forceinline__ float bhi(unsigned u) { return __uint_as_float(u & 0xffff0000u); }

// ---- K1: fused CSR rowptr build + Xp = bf16(X @ W) via MFMA ---------------
// B fragments (W) loaded ONCE per wave; block loops row-tiles grid-stride.
__global__ __launch_bounds__(256) void gemm_rowptr(
    const float* __restrict__ X, const float* __restrict__ W,
    const int* __restrict__ row, unsigned short* __restrict__ Xpb,
    int* __restrict__ rp, int N, int E)
{
    // rowptr: grid-stride over edges (row[] sorted, every row non-empty)
    {
        const int stride = gridDim.x * 256;
        for (int e = blockIdx.x * 256 + threadIdx.x; e < E; e += stride) {
            int r = row[e];
            if (e == 0)                rp[r] = 0;
            else if (row[e - 1] != r)  rp[r] = e;
            if (e == E - 1)            rp[N] = E;
        }
    }

    const int lane = threadIdx.x & 63;
    const int wv   = threadIdx.x >> 6;       // 0..3: col block
    const int m    = lane & 15;              // A-row / B-col / D-col
    const int kb   = (lane >> 4) << 3;       // k-base: 0,8,16,24

    // B fragments: lane holds W[kb + j (+32)][16*wv + m]  (loop-invariant)
    const float* wc = W + (size_t)kb * 64 + 16 * wv + m;
    short8 b0, b1;
#pragma unroll
    for (int j = 0; j < 8; ++j) b0[j] = f2bf(wc[j * 64]);
#pragma unroll
    for (int j = 0; j < 8; ++j) b1[j] = f2bf(wc[(j + 32) * 64]);

    const int ntiles = (N + 15) >> 4;
    for (int t = blockIdx.x; t < ntiles; t += gridDim.x) {
        const int r0 = t << 4;
        const int rA = min(r0 + m, N - 1);               // clamped load row
        const float* xr = X + (size_t)rA * 64 + kb;
        float4 aL0 = *(const float4*)(xr);
        float4 aH0 = *(const float4*)(xr + 4);
        float4 aL1 = *(const float4*)(xr + 32);
        float4 aH1 = *(const float4*)(xr + 36);
        short8 a0, a1;
        a0[0]=f2bf(aL0.x); a0[1]=f2bf(aL0.y); a0[2]=f2bf(aL0.z); a0[3]=f2bf(aL0.w);
        a0[4]=f2bf(aH0.x); a0[5]=f2bf(aH0.y); a0[6]=f2bf(aH0.z); a0[7]=f2bf(aH0.w);
        a1[0]=f2bf(aL1.x); a1[1]=f2bf(aL1.y); a1[2]=f2bf(aL1.z); a1[3]=f2bf(aL1.w);
        a1[4]=f2bf(aH1.x); a1[5]=f2bf(aH1.y); a1[6]=f2bf(aH1.z); a1[7]=f2bf(aH1.w);

        f32x4 acc = {0.f, 0.f, 0.f, 0.f};
        acc = __builtin_amdgcn_mfma_f32_16x16x32_bf16(a0, b0, acc, 0, 0, 0);
        acc = __builtin_amdgcn_mfma_f32_16x16x32_bf16(a1, b1, acc, 0, 0, 0);

        // D: col = 16*wv + m, row = r0 + (lane>>4)*4 + j
        const int rD = r0 + ((lane >> 4) << 2);
        unsigned short* o = Xpb + (size_t)rD * 64 + 16 * wv + m;
#pragma unroll
        for (int j = 0; j < 4; ++j)
            if (rD + j < N) o[j * 64] = f2bf(acc[j]);
    }
}

// ---- K2: aggregation. 4 rows/wave, 16 lanes/row, 4 bf16 features/lane -----
// Depth-2 gather pipeline: 8 Xp-gathers + 4 col loads outstanding per wave.
#define AGG_STEP(G, OFF)                                                          \
    {                                                                             \
        float x0 = blo(G.x), x1 = bhi(G.x), x2 = blo(G.y), x3 = bhi(G.y);         \
        float p = x0 * xr0;                                                       \
        p = fmaf(x1, xr1, p);                                                     \
        p = fmaf(x2, xr2, p);                                                     \
        p = fmaf(x3, xr3, p);                                                     \
        p += __int_as_float(__builtin_amdgcn_ds_swizzle(__float_as_int(p), 0x041F)); \
        p += __int_as_float(__builtin_amdgcn_ds_swizzle(__float_as_int(p), 0x081F)); \
        p += __int_as_float(__builtin_amdgcn_ds_swizzle(__float_as_int(p), 0x101F)); \
        p += __int_as_float(__builtin_amdgcn_ds_swizzle(__float_as_int(p), 0x201F)); \
        float att = __expf(p * aw);                                               \
        att = (e + OFF < end) ? att : 0.f;                                        \
        acc0 = fmaf(att, x0, acc0);                                               \
        acc1 = fmaf(att, x1, acc1);                                               \
        acc2 = fmaf(att, x2, acc2);                                               \
        acc3 = fmaf(att, x3, acc3);                                               \
        rs += att;                                                                \
    }

__global__ __launch_bounds__(256) void agg(
    const unsigned short* __restrict__ Xpb, const int* __restrict__ rp,
    const int* __restrict__ col, const float* __restrict__ attw,
    float* __restrict__ out, int N)
{
    const int lane = threadIdx.x & 63;
    const int t    = lane & 15;                                   // pos in group
    const int wid  = (int)((blockIdx.x * blockDim.x + threadIdx.x) >> 6);
    const int r    = (wid << 2) + (lane >> 4);
    if ((wid << 2) >= N) return;
    const int  rr    = (r < N) ? r : (N - 1);
    const bool rowok = (r < N);

    const float aw    = attw[0];
    const int   start = rp[rr];
    const int   end   = rowok ? rp[rr + 1] : start;
    const int   cap   = (end > start) ? (end - 1) : start;        // clamp target

    const char* xb = (const char*)Xpb + (t << 3);                 // lane byte base
    uint2 xw = *(const uint2*)(xb + ((size_t)rr << 7));
    const float xr0 = blo(xw.x), xr1 = bhi(xw.x), xr2 = blo(xw.y), xr3 = bhi(xw.y);

    float acc0 = 0.f, acc1 = 0.f, acc2 = 0.f, acc3 = 0.f, rs = 0.f;

    // ---- pipeline prologue: packets 0 and 1 gathered, packet-2 cols loaded
    int c0 = col[min(start,     cap)];
    int c1 = col[min(start + 1, cap)];
    int c2 = col[min(start + 2, cap)];
    int c3 = col[min(start + 3, cap)];
    uint2 g0 = *(const uint2*)(xb + ((size_t)c0 << 7));
    uint2 g1 = *(const uint2*)(xb + ((size_t)c1 << 7));
    uint2 g2 = *(const uint2*)(xb + ((size_t)c2 << 7));
    uint2 g3 = *(const uint2*)(xb + ((size_t)c3 << 7));
    c0 = col[min(start + 4, cap)];
    c1 = col[min(start + 5, cap)];
    c2 = col[min(start + 6, cap)];
    c3 = col[min(start + 7, cap)];
    uint2 h0 = *(const uint2*)(xb + ((size_t)c0 << 7));
    uint2 h1 = *(const uint2*)(xb + ((size_t)c1 << 7));
    uint2 h2 = *(const uint2*)(xb + ((size_t)c2 << 7));
    uint2 h3 = *(const uint2*)(xb + ((size_t)c3 << 7));
    int n0 = col[min(start +  8, cap)];
    int n1 = col[min(start +  9, cap)];
    int n2 = col[min(start + 10, cap)];
    int n3 = col[min(start + 11, cap)];

    for (int e = start; e < end; e += 4) {
        // issue gathers for packet e+8 (cols resident in n*)
        uint2 G0 = *(const uint2*)(xb + ((size_t)n0 << 7));
        uint2 G1 = *(const uint2*)(xb + ((size_t)n1 << 7));
        uint2 G2 = *(const uint2*)(xb + ((size_t)n2 << 7));
        uint2 G3 = *(const uint2*)(xb + ((size_t)n3 << 7));
        // issue cols for packet e+12
        int m0 = col[min(e + 12, cap)];
        int m1 = col[min(e + 13, cap)];
        int m2 = col[min(e + 14, cap)];
        int m3 = col[min(e + 15, cap)];

        AGG_STEP(g0, 0)
        AGG_STEP(g1, 1)
        AGG_STEP(g2, 2)
        AGG_STEP(g3, 3)

        g0 = h0; g1 = h1; g2 = h2; g3 = h3;
        h0 = G0; h1 = G1; h2 = G2; h3 = G3;
        n0 = m0; n1 = m1; n2 = m2; n3 = m3;
    }

    if (rowok) {
        float inv = 1.0f / rs;
        *(float4*)(out + ((size_t)r << 6) + (t << 2)) =
            make_float4(acc0 * inv, acc1 * inv, acc2 * inv, acc3 * inv);
    }
}

// ---------------------------------------------------------------------------
extern "C" void kernel_launch(void* const* d_in, const int* in_sizes, int n_in,
                              void* d_out, int out_size, void* d_ws, size_t ws_size,
                              hipStream_t stream)
{
    const float* X    = (const float*)d_in[0];
    const float* W    = (const float*)d_in[1];
    const float* attw = (const float*)d_in[2];
    const int*   row  = (const int*)d_in[3];
    const int*   col  = (const int*)d_in[4];
    float*       out  = (float*)d_out;

    const int N = in_sizes[0] / 64;
    const int E = in_sizes[3];

    unsigned short* Xpb = (unsigned short*)d_ws;                       // N*64 bf16
    int* rp = (int*)((char*)d_ws + (size_t)N * 64 * sizeof(unsigned short));

    gemm_rowptr<<<2048, 256, 0, stream>>>(X, W, row, Xpb, rp, N, E);

    int waves = (N + 3) / 4;
    int gb2   = (waves * 64 + 255) / 256;
    agg<<<gb2, 256, 0, stream>>>(Xpb, rp, col, attw, out, N);
}